// Round 1
// baseline (657.571 us; speedup 1.0000x reference)
//
#include <hip/hip_runtime.h>

#define IH 480
#define IW 640
#define NB 8
#define OC 64
#define KK 5
#define PD 2

__global__ __launch_bounds__(256) void ndconv_kernel(
    const float* __restrict__ x,      // [8,1,480,640]
    const float* __restrict__ wgt,    // [1,64,5,5] -> flat [64,25]
    float* __restrict__ out)          // [8,64,480,640]
{
    int idx = blockIdx.x * blockDim.x + threadIdx.x;   // pixel index over B*H*W
    if (idx >= NB * IH * IW) return;
    int w = idx % IW;
    int t = idx / IW;
    int h = t % IH;
    int b = t / IH;

    const float* xb = x + (size_t)b * (IH * IW);

    float patch[KK * KK];
    float sum = 0.0f;
    float cnt = 0.0f;
#pragma unroll
    for (int kh = 0; kh < KK; ++kh) {
        int hh = h + kh - PD;
        bool hv = (unsigned)hh < (unsigned)IH;
#pragma unroll
        for (int kw = 0; kw < KK; ++kw) {
            int ww = w + kw - PD;
            bool v = hv && ((unsigned)ww < (unsigned)IW);
            float val = v ? xb[hh * IW + ww] : 0.0f;
            patch[kh * KK + kw] = val;
            sum += val;
            cnt += (val > 1e-4f) ? 1.0f : 0.0f;
        }
    }
    float mean = sum / (cnt + 1e-6f);

    // t_k = (mean - p_k) * mask_k
#pragma unroll
    for (int k = 0; k < KK * KK; ++k) {
        float v = patch[k];
        patch[k] = (v > 1e-4f) ? (mean - v) : 0.0f;
    }

    float* ob = out + (size_t)b * OC * (IH * IW) + (size_t)h * IW + w;

    // 64 channels, 25-FMA dot each; weights are wave-uniform (scalar loads).
#pragma unroll 4
    for (int o = 0; o < OC; ++o) {
        const float* wo = wgt + o * (KK * KK);
        float acc = 0.0f;
#pragma unroll
        for (int k = 0; k < KK * KK; ++k)
            acc = fmaf(wo[k], patch[k], acc);
        ob[(size_t)o * (IH * IW)] = acc;
    }
}

extern "C" void kernel_launch(void* const* d_in, const int* in_sizes, int n_in,
                              void* d_out, int out_size, void* d_ws, size_t ws_size,
                              hipStream_t stream) {
    const float* x   = (const float*)d_in[0];
    const float* wgt = (const float*)d_in[1];
    float* out = (float*)d_out;

    const int total = NB * IH * IW;           // 2,457,600 pixels
    const int block = 256;
    const int grid = (total + block - 1) / block;  // 9600 blocks
    ndconv_kernel<<<grid, block, 0, stream>>>(x, wgt, out);
}